// Round 1
// baseline (474.738 us; speedup 1.0000x reference)
//
#include <hip/hip_runtime.h>
#include <hip/hip_bf16.h>

#define NN 8192
#define DIM 128
#define NWORDS (NN / 32)   // 256 bitmask words per row
#define KS 4               // split-K factor for the PV GEMM

typedef __attribute__((ext_vector_type(8))) short bf16x8;
typedef __attribute__((ext_vector_type(4))) float f32x4;

static __device__ inline short f2bf(float x) {
    __hip_bfloat16 b = __float2bfloat16(x);
    return *reinterpret_cast<short*>(&b);
}

// ---------------------------------------------------------------------------
// K1: Wh = h @ W^T  (per 16-row block); writes WhbT (bf16, [DIM][NN]) for the
// PV GEMM's B operand, plus a1 = Wh@a[:128], a2 = Wh@a[128:], E1=exp(a2),
// E2=exp(0.2*a2).
// ---------------------------------------------------------------------------
__global__ __launch_bounds__(256) void k1_wh(const float* __restrict__ h,
                                             const float* __restrict__ W,
                                             const float* __restrict__ a,
                                             __hip_bfloat16* __restrict__ whbT,
                                             float* __restrict__ a1g,
                                             float* __restrict__ a2g,
                                             float* __restrict__ E1g,
                                             float* __restrict__ E2g) {
    __shared__ float WT[128][129];          // transposed W, +1 pad (bank-safe)
    __shared__ float h_s[16][128];
    __shared__ float a_s[256];
    __shared__ float red[256];
    __shared__ __hip_bfloat16 wt_s[128][16];

    const int tid = threadIdx.x;
    const int r0 = blockIdx.x * 16;

    for (int idx = tid; idx < 128 * 128; idx += 256) {
        int d = idx >> 7, k = idx & 127;
        WT[k][d] = W[idx];                  // W[d][k] row-major read, coalesced
    }
    for (int idx = tid; idx < 16 * 128; idx += 256)
        h_s[idx >> 7][idx & 127] = h[(size_t)(r0 + (idx >> 7)) * DIM + (idx & 127)];
    a_s[tid] = a[tid];
    __syncthreads();

    const int d = tid & 127;
    const int g = tid >> 7;                 // 0/1 -> rows g*8 .. g*8+7
    float acc[8] = {0, 0, 0, 0, 0, 0, 0, 0};
    for (int k = 0; k < 128; ++k) {
        float wv = WT[k][d];
        #pragma unroll
        for (int rr = 0; rr < 8; ++rr)
            acc[rr] += h_s[g * 8 + rr][k] * wv;
    }

    // bf16 Wh^T for GEMM B operand
    #pragma unroll
    for (int rr = 0; rr < 8; ++rr)
        wt_s[d][g * 8 + rr] = __float2bfloat16(acc[rr]);
    __syncthreads();
    for (int idx = tid; idx < 128 * 16; idx += 256) {
        int dd = idx >> 4, r = idx & 15;
        whbT[(size_t)dd * NN + r0 + r] = wt_s[dd][r];
    }

    // a1/a2 reductions (f32-exact path for the softmax inputs)
    for (int rr = 0; rr < 8; ++rr) {
        const int row = r0 + g * 8 + rr;
        red[tid] = acc[rr] * a_s[d];
        __syncthreads();
        for (int s = 64; s >= 1; s >>= 1) {
            if ((tid & 127) < s) red[tid] += red[tid + s];
            __syncthreads();
        }
        if ((tid & 127) == 0) a1g[row] = red[tid];
        __syncthreads();
        red[tid] = acc[rr] * a_s[128 + d];
        __syncthreads();
        for (int s = 64; s >= 1; s >>= 1) {
            if ((tid & 127) < s) red[tid] += red[tid + s];
            __syncthreads();
        }
        if ((tid & 127) == 0) {
            float v = red[tid];
            a2g[row] = v;
            E1g[row] = expf(v);
            E2g[row] = expf(0.2f * v);
        }
        __syncthreads();
    }
}

// ---------------------------------------------------------------------------
// K2: pack adjacency to bitmask via wave ballot (coalesced 4B/lane reads)
// ---------------------------------------------------------------------------
__global__ __launch_bounds__(256) void k2_pack(const int* __restrict__ adj,
                                               unsigned* __restrict__ bm) {
    const int i = blockIdx.x;
    const int* row = adj + (size_t)i * NN;
    for (int j = threadIdx.x; j < NN; j += 256) {
        int v = row[j];
        unsigned long long m = __ballot(v != 0);
        int l = threadIdx.x & 63;
        if ((l & 31) == 0)
            bm[i * NWORDS + (j >> 5)] = (unsigned)(m >> (l & 32));
    }
}

// ---------------------------------------------------------------------------
// K3: per-row masked softmax. One block per row.
//   m_i = leaky(a1_i + max_nbr a2_j)  (leaky is monotone)
//   S   = exp(a1_i-m)*sum_{nbr,pos} E1_j + exp(0.2 a1_i-m)*sum_{nbr,neg} E2_j
//   alpha_ij = bit ? (pos ? c1*E1_j : c2*E2_j) : 0
// ---------------------------------------------------------------------------
__device__ inline float waveReduceSum(float v) {
    #pragma unroll
    for (int o = 32; o >= 1; o >>= 1) v += __shfl_xor(v, o, 64);
    return v;
}
__device__ inline float waveReduceMax(float v) {
    #pragma unroll
    for (int o = 32; o >= 1; o >>= 1) v = fmaxf(v, __shfl_xor(v, o, 64));
    return v;
}

__global__ __launch_bounds__(256) void k3_softmax(const unsigned* __restrict__ bm,
                                                  const float* __restrict__ a1g,
                                                  const float* __restrict__ a2g,
                                                  const float* __restrict__ E1g,
                                                  const float* __restrict__ E2g,
                                                  float* __restrict__ alpha) {
    __shared__ float sredM[4], sred1[4], sred2[4];
    __shared__ float cbc[2];

    const int i = blockIdx.x;
    const int tid = threadIdx.x;
    const float a1i = a1g[i];
    const unsigned* brow = bm + (size_t)i * NWORDS;

    float M = -INFINITY, s1 = 0.f, s2 = 0.f;
    for (int j = tid; j < NN; j += 256) {
        unsigned w = brow[j >> 5];
        if ((w >> (j & 31)) & 1u) {
            float x2 = a2g[j];
            M = fmaxf(M, x2);
            if (a1i + x2 >= 0.f) s1 += E1g[j];
            else                 s2 += E2g[j];
        }
    }

    const int wid = tid >> 6, lane = tid & 63;
    M = waveReduceMax(M);
    s1 = waveReduceSum(s1);
    s2 = waveReduceSum(s2);
    if (lane == 0) { sredM[wid] = M; sred1[wid] = s1; sred2[wid] = s2; }
    __syncthreads();
    if (tid == 0) {
        float Mm = fmaxf(fmaxf(sredM[0], sredM[1]), fmaxf(sredM[2], sredM[3]));
        float S1 = (sred1[0] + sred1[1]) + (sred1[2] + sred1[3]);
        float S2 = (sred2[0] + sred2[1]) + (sred2[2] + sred2[3]);
        if (Mm == -INFINITY) {          // no neighbors: alpha row is all zero
            cbc[0] = 0.f; cbc[1] = 0.f;
        } else {
            float x = a1i + Mm;
            float m = (x >= 0.f) ? x : 0.2f * x;
            float e1 = expf(a1i - m);
            float e2 = expf(0.2f * a1i - m);
            float S = e1 * S1 + e2 * S2;
            cbc[0] = e1 / S; cbc[1] = e2 / S;
        }
    }
    __syncthreads();
    const float c1 = cbc[0], c2 = cbc[1];

    float* arow = alpha + (size_t)i * NN;
    for (int j = tid; j < NN; j += 256) {
        unsigned w = brow[j >> 5];
        float al = 0.f;
        if ((w >> (j & 31)) & 1u) {
            float x2 = a2g[j];
            al = (a1i + x2 >= 0.f) ? c1 * E1g[j] : c2 * E2g[j];
        }
        arow[j] = al;
    }
}

// ---------------------------------------------------------------------------
// K4: out = alpha @ Wh via MFMA 16x16x32 bf16, split-K into KS partials.
// A-frag: lane holds alpha[m0+(l&15)][k0+8*(l>>4)+e]; B-frag from WhbT
// (col-major Wh) so the 8 k-elements are contiguous. Deterministic (no
// atomics): partials reduced by K5.
// ---------------------------------------------------------------------------
__global__ __launch_bounds__(256) void k4_gemm(const float* __restrict__ alpha,
                                               const __hip_bfloat16* __restrict__ whbT,
                                               float* __restrict__ part) {
    const int mt = blockIdx.x;              // 0..127  (64 rows each)
    const int ks = blockIdx.y;              // 0..KS-1
    const int tid = threadIdx.x;
    const int wv = tid >> 6, lane = tid & 63;
    const int m0 = mt * 64 + wv * 16;
    const int kbase = ks * (NN / KS);

    f32x4 acc[8];
    #pragma unroll
    for (int n = 0; n < 8; ++n) acc[n] = (f32x4){0.f, 0.f, 0.f, 0.f};

    const int rowA = m0 + (lane & 15);
    const int ksub = (lane >> 4) * 8;
    const float* aptr = alpha + (size_t)rowA * NN + kbase + ksub;
    const short* wb = reinterpret_cast<const short*>(whbT);

    for (int kk = 0; kk < NN / KS; kk += 32) {
        f32x4 lo = *(const f32x4*)(aptr + kk);
        f32x4 hi = *(const f32x4*)(aptr + kk + 4);
        bf16x8 af;
        af[0] = f2bf(lo.x); af[1] = f2bf(lo.y); af[2] = f2bf(lo.z); af[3] = f2bf(lo.w);
        af[4] = f2bf(hi.x); af[5] = f2bf(hi.y); af[6] = f2bf(hi.z); af[7] = f2bf(hi.w);
        #pragma unroll
        for (int n = 0; n < 8; ++n) {
            int col = n * 16 + (lane & 15);
            bf16x8 bf = *(const bf16x8*)(wb + (size_t)col * NN + kbase + kk + ksub);
            acc[n] = __builtin_amdgcn_mfma_f32_16x16x32_bf16(af, bf, acc[n], 0, 0, 0);
        }
    }

    float* pbase = part + (size_t)ks * NN * DIM;
    const int rbase = m0 + (lane >> 4) * 4;
    #pragma unroll
    for (int n = 0; n < 8; ++n) {
        #pragma unroll
        for (int q = 0; q < 4; ++q)
            pbase[(size_t)(rbase + q) * DIM + n * 16 + (lane & 15)] = acc[n][q];
    }
}

// ---------------------------------------------------------------------------
// K5: reduce split-K partials -> out
// ---------------------------------------------------------------------------
__global__ __launch_bounds__(256) void k5_reduce(const float* __restrict__ part,
                                                 float* __restrict__ out) {
    const int idx = blockIdx.x * 256 + threadIdx.x;    // < NN*DIM
    float s = 0.f;
    #pragma unroll
    for (int ks = 0; ks < KS; ++ks) s += part[(size_t)ks * NN * DIM + idx];
    out[idx] = s;
}

// ---------------------------------------------------------------------------
extern "C" void kernel_launch(void* const* d_in, const int* in_sizes, int n_in,
                              void* d_out, int out_size, void* d_ws, size_t ws_size,
                              hipStream_t stream) {
    const float* h   = (const float*)d_in[0];
    const int*   adj = (const int*)d_in[1];
    const float* W   = (const float*)d_in[2];
    const float* a   = (const float*)d_in[3];

    float* out   = (float*)d_out;
    float* alpha = out + (size_t)NN * DIM;   // outputs concatenated: out, alpha

    char* ws = (char*)d_ws;
    unsigned*        bm    = (unsigned*)(ws);                     // 8 MB
    __hip_bfloat16*  whbT  = (__hip_bfloat16*)(ws + 8388608);     // 2 MB
    float*           a1g   = (float*)(ws + 10485760);             // 32 KB
    float*           a2g   = (float*)(ws + 10518528);             // 32 KB
    float*           E1g   = (float*)(ws + 10551296);             // 32 KB
    float*           E2g   = (float*)(ws + 10584064);             // 32 KB
    float*           part  = (float*)(ws + 10616832);             // KS*4 MB = 16 MB

    k1_wh<<<NN / 16, 256, 0, stream>>>(h, W, a, whbT, a1g, a2g, E1g, E2g);
    k2_pack<<<NN, 256, 0, stream>>>(adj, bm);
    k3_softmax<<<NN, 256, 0, stream>>>(bm, a1g, a2g, E1g, E2g, alpha);
    k4_gemm<<<dim3(NN / 64, KS), 256, 0, stream>>>(alpha, whbT, part);
    k5_reduce<<<NN * DIM / 256, 256, 0, stream>>>(part, out);
}

// Round 2
// 248.654 us; speedup vs baseline: 1.9092x; 1.9092x over previous
//
#include <hip/hip_runtime.h>
#include <hip/hip_bf16.h>

#define NN 8192
#define DIM 128
#define KC 256          // k-chunk width in fused pass B
#define RPB 16          // rows per block in fused kernel

typedef __attribute__((ext_vector_type(8))) short bf16x8;
typedef __attribute__((ext_vector_type(4))) float f32x4;
typedef __attribute__((ext_vector_type(4))) int i32x4;
typedef __attribute__((ext_vector_type(4))) unsigned short u16x4;

static __device__ inline unsigned short f2bf(float x) {
    __hip_bfloat16 b = __float2bfloat16(x);
    return *reinterpret_cast<unsigned short*>(&b);
}

// ---------------------------------------------------------------------------
// K0: w1 = W^T a[:128], w2 = W^T a[128:]   (a1 = Wh@a1v == h@(W^T a1v))
// ---------------------------------------------------------------------------
__global__ void k0_wvec(const float* __restrict__ W, const float* __restrict__ a,
                        float* __restrict__ w12) {
    const int in = threadIdx.x;          // 128 threads
    float s1 = 0.f, s2 = 0.f;
    for (int o = 0; o < 128; ++o) {
        float wv = W[o * 128 + in];
        s1 += wv * a[o];
        s2 += wv * a[o + 128];
    }
    w12[in] = s1;
    w12[128 + in] = s2;
}

// ---------------------------------------------------------------------------
// K1: Wh = h @ W^T -> whbT (bf16, [DIM][NN] col-major for MFMA B-frags)
// ---------------------------------------------------------------------------
__global__ __launch_bounds__(256) void k1_wh(const float* __restrict__ h,
                                             const float* __restrict__ W,
                                             __hip_bfloat16* __restrict__ whbT) {
    __shared__ float WT[128][129];
    __shared__ float h_s[16][128];
    __shared__ __hip_bfloat16 wt_s[128][16];

    const int tid = threadIdx.x;
    const int r0 = blockIdx.x * 16;

    for (int idx = tid; idx < 128 * 128; idx += 256) {
        int d = idx >> 7, k = idx & 127;
        WT[k][d] = W[idx];
    }
    for (int idx = tid; idx < 16 * 128; idx += 256)
        h_s[idx >> 7][idx & 127] = h[(size_t)(r0 + (idx >> 7)) * DIM + (idx & 127)];
    __syncthreads();

    const int d = tid & 127;
    const int g = tid >> 7;
    float acc[8] = {0, 0, 0, 0, 0, 0, 0, 0};
    for (int k = 0; k < 128; ++k) {
        float wv = WT[k][d];
        #pragma unroll
        for (int rr = 0; rr < 8; ++rr)
            acc[rr] += h_s[g * 8 + rr][k] * wv;
    }
    #pragma unroll
    for (int rr = 0; rr < 8; ++rr)
        wt_s[d][g * 8 + rr] = __float2bfloat16(acc[rr]);
    __syncthreads();
    for (int idx = tid; idx < 128 * 16; idx += 256) {
        int dd = idx >> 4, r = idx & 15;
        whbT[(size_t)dd * NN + r0 + r] = wt_s[dd][r];
    }
}

// ---------------------------------------------------------------------------
// K2a: per-row a1 = h.w1, a2 = h.w2, E1 = exp(a2), E2 = exp(0.2 a2)
// one wave per row, shuffle reduce
// ---------------------------------------------------------------------------
__global__ __launch_bounds__(256) void k2a_rows(const float* __restrict__ h,
                                                const float* __restrict__ w12,
                                                float* __restrict__ a1g,
                                                float* __restrict__ a2g,
                                                float* __restrict__ E1g,
                                                float* __restrict__ E2g) {
    const int wid = threadIdx.x >> 6, lane = threadIdx.x & 63;
    const int i = blockIdx.x * 4 + wid;
    const float* hr = h + (size_t)i * DIM;
    float h0 = hr[lane], h1 = hr[lane + 64];
    float s1 = h0 * w12[lane] + h1 * w12[lane + 64];
    float s2 = h0 * w12[128 + lane] + h1 * w12[192 + lane];
    #pragma unroll
    for (int o = 32; o >= 1; o >>= 1) {
        s1 += __shfl_xor(s1, o, 64);
        s2 += __shfl_xor(s2, o, 64);
    }
    if (lane == 0) {
        a1g[i] = s1;
        a2g[i] = s2;
        E1g[i] = expf(s2);
        E2g[i] = expf(0.2f * s2);
    }
}

// ---------------------------------------------------------------------------
// FK: fused adj-scan + masked softmax + alpha write + PV MFMA.
// 512 blocks x 16 rows, 512 threads (8 waves). Bitmask lives only in LDS.
// Bit layout (from 4x ballot over int4 loads): col j -> word (j>>8)*8 +
// (j&3)*2 + ((j>>7)&1), bit (j>>2)&31.
// ---------------------------------------------------------------------------
__global__ __launch_bounds__(512) void fk(const int* __restrict__ adj,
                                          const float* __restrict__ a1g,
                                          const float* __restrict__ a2g,
                                          const float* __restrict__ E1g,
                                          const float* __restrict__ E2g,
                                          const __hip_bfloat16* __restrict__ whbT,
                                          float* __restrict__ alpha,
                                          float* __restrict__ out) {
    __shared__ unsigned bm[RPB][NN / 32];                 // 16 KB
    __shared__ __hip_bfloat16 abuf[2][RPB][KC + 8];       // 2 x 8.25 KB
    __shared__ float crow[RPB][4];                        // c1, c2, a1i

    const int tid = threadIdx.x;
    const int wv = tid >> 6, lane = tid & 63;
    const int r0 = blockIdx.x * RPB;

    // ---- pass A: stream adj, build bitmask + row stats -----------------
    #pragma unroll
    for (int rr = 0; rr < 2; ++rr) {
        const int r = wv * 2 + rr;
        const int gi = r0 + r;
        const float a1i = a1g[gi];
        const int* arow = adj + (size_t)gi * NN;
        float M = -INFINITY, s1 = 0.f, s2 = 0.f;
        for (int it = 0; it < NN / 256; ++it) {
            const int j0 = it * 256 + lane * 4;
            i32x4 v = __builtin_nontemporal_load((const i32x4*)(arow + j0));
            unsigned long long m0 = __ballot(v.x != 0);
            unsigned long long m1 = __ballot(v.y != 0);
            unsigned long long m2 = __ballot(v.z != 0);
            unsigned long long m3 = __ballot(v.w != 0);
            if (lane == 0) {
                bm[r][it * 8 + 0] = (unsigned)m0;
                bm[r][it * 8 + 2] = (unsigned)m1;
                bm[r][it * 8 + 4] = (unsigned)m2;
                bm[r][it * 8 + 6] = (unsigned)m3;
            } else if (lane == 32) {
                bm[r][it * 8 + 1] = (unsigned)(m0 >> 32);
                bm[r][it * 8 + 3] = (unsigned)(m1 >> 32);
                bm[r][it * 8 + 5] = (unsigned)(m2 >> 32);
                bm[r][it * 8 + 7] = (unsigned)(m3 >> 32);
            }
            f32x4 x2 = *(const f32x4*)(a2g + j0);
            f32x4 e1 = *(const f32x4*)(E1g + j0);
            f32x4 e2 = *(const f32x4*)(E2g + j0);
            if (v.x) { M = fmaxf(M, x2.x); if (a1i + x2.x >= 0.f) s1 += e1.x; else s2 += e2.x; }
            if (v.y) { M = fmaxf(M, x2.y); if (a1i + x2.y >= 0.f) s1 += e1.y; else s2 += e2.y; }
            if (v.z) { M = fmaxf(M, x2.z); if (a1i + x2.z >= 0.f) s1 += e1.z; else s2 += e2.z; }
            if (v.w) { M = fmaxf(M, x2.w); if (a1i + x2.w >= 0.f) s1 += e1.w; else s2 += e2.w; }
        }
        #pragma unroll
        for (int o = 32; o >= 1; o >>= 1) {
            M = fmaxf(M, __shfl_xor(M, o, 64));
            s1 += __shfl_xor(s1, o, 64);
            s2 += __shfl_xor(s2, o, 64);
        }
        if (lane == 0) {
            float c1 = 0.f, c2 = 0.f;
            if (M != -INFINITY) {
                float x = a1i + M;
                float mm = (x >= 0.f) ? x : 0.2f * x;
                float e1v = expf(a1i - mm);
                float e2v = expf(0.2f * a1i - mm);
                float S = e1v * s1 + e2v * s2;
                c1 = e1v / S;
                c2 = e2v / S;
            }
            crow[r][0] = c1; crow[r][1] = c2; crow[r][2] = a1i;
        }
    }
    __syncthreads();

    // ---- pass B: per 256-col chunk: alpha -> global + LDS bf16; MFMA ----
    f32x4 acc = (f32x4){0.f, 0.f, 0.f, 0.f};
    const int n0 = wv * 16;
    const short* bptr = reinterpret_cast<const short*>(whbT) +
                        (size_t)(n0 + (lane & 15)) * NN + 8 * (lane >> 4);

    for (int kc = 0; kc < NN; kc += KC) {
        const int dbuf = (kc >> 8) & 1;
        #pragma unroll
        for (int v = 0; v < 2; ++v) {
            const int vid = v * 512 + tid;
            const int r = vid >> 6;
            const int c4 = (vid & 63) << 2;
            const int j = kc + c4;
            const unsigned p = (c4 >> 2) & 31;
            const int wb0 = ((j >> 8) << 3) | ((j >> 7) & 1);
            const unsigned b0 = (bm[r][wb0 + 0] >> p) & 1u;
            const unsigned b1 = (bm[r][wb0 + 2] >> p) & 1u;
            const unsigned b2 = (bm[r][wb0 + 4] >> p) & 1u;
            const unsigned b3 = (bm[r][wb0 + 6] >> p) & 1u;
            const float c1 = crow[r][0], c2 = crow[r][1], a1i = crow[r][2];
            f32x4 x2 = *(const f32x4*)(a2g + j);
            f32x4 e1 = *(const f32x4*)(E1g + j);
            f32x4 e2 = *(const f32x4*)(E2g + j);
            f32x4 al;
            al.x = b0 ? ((a1i + x2.x >= 0.f) ? c1 * e1.x : c2 * e2.x) : 0.f;
            al.y = b1 ? ((a1i + x2.y >= 0.f) ? c1 * e1.y : c2 * e2.y) : 0.f;
            al.z = b2 ? ((a1i + x2.z >= 0.f) ? c1 * e1.z : c2 * e2.z) : 0.f;
            al.w = b3 ? ((a1i + x2.w >= 0.f) ? c1 * e1.w : c2 * e2.w) : 0.f;
            __builtin_nontemporal_store(al, (f32x4*)(alpha + (size_t)(r0 + r) * NN + j));
            u16x4 ub;
            ub.x = f2bf(al.x); ub.y = f2bf(al.y); ub.z = f2bf(al.z); ub.w = f2bf(al.w);
            *(u16x4*)(&abuf[dbuf][r][c4]) = ub;
        }
        __syncthreads();
        #pragma unroll
        for (int kk = 0; kk < KC; kk += 32) {
            bf16x8 af = *(const bf16x8*)(&abuf[dbuf][lane & 15][kk + 8 * (lane >> 4)]);
            bf16x8 bf = *(const bf16x8*)(bptr + kc + kk);
            acc = __builtin_amdgcn_mfma_f32_16x16x32_bf16(af, bf, acc, 0, 0, 0);
        }
    }

    const int col = n0 + (lane & 15);
    const int rb = (lane >> 4) * 4;
    #pragma unroll
    for (int q = 0; q < 4; ++q)
        out[(size_t)(r0 + rb + q) * DIM + col] = acc[q];
}

// ---------------------------------------------------------------------------
extern "C" void kernel_launch(void* const* d_in, const int* in_sizes, int n_in,
                              void* d_out, int out_size, void* d_ws, size_t ws_size,
                              hipStream_t stream) {
    const float* h   = (const float*)d_in[0];
    const int*   adj = (const int*)d_in[1];
    const float* W   = (const float*)d_in[2];
    const float* a   = (const float*)d_in[3];

    float* out   = (float*)d_out;
    float* alpha = out + (size_t)NN * DIM;

    char* ws = (char*)d_ws;
    __hip_bfloat16* whbT = (__hip_bfloat16*)(ws);              // 2 MB
    float* a1g = (float*)(ws + 2097152);                       // 32 KB
    float* a2g = (float*)(ws + 2097152 + 32768);
    float* E1g = (float*)(ws + 2097152 + 2 * 32768);
    float* E2g = (float*)(ws + 2097152 + 3 * 32768);
    float* w12 = (float*)(ws + 2097152 + 4 * 32768);           // 1 KB

    k0_wvec<<<1, 128, 0, stream>>>(W, a, w12);
    k1_wh<<<NN / 16, 256, 0, stream>>>(h, W, whbT);
    k2a_rows<<<NN / 4, 256, 0, stream>>>(h, w12, a1g, a2g, E1g, E2g);
    fk<<<NN / RPB, 512, 0, stream>>>(adj, a1g, a2g, E1g, E2g, whbT, alpha, out);
}

// Round 3
// 205.421 us; speedup vs baseline: 2.3110x; 1.2105x over previous
//
#include <hip/hip_runtime.h>
#include <hip/hip_bf16.h>

#define NN 8192
#define DIM 128
#define KS 4            // split-K factor for PV
#define KSL (NN / KS)   // 2048 k per slice
#define RPB 32          // rows per SB block
#define KC 256          // k-chunk width in SB

typedef __attribute__((ext_vector_type(8))) short bf16x8;
typedef __attribute__((ext_vector_type(4))) float f32x4;
typedef __attribute__((ext_vector_type(4))) int i32x4;
typedef __attribute__((ext_vector_type(4))) unsigned int u32x4;
typedef __attribute__((ext_vector_type(4))) unsigned short u16x4;

static __device__ inline unsigned short f2bf(float x) {
    __hip_bfloat16 b = __float2bfloat16(x);
    return *reinterpret_cast<unsigned short*>(&b);
}

// ---------------------------------------------------------------------------
// K0: w1 = W^T a[:128], w2 = W^T a[128:]
// ---------------------------------------------------------------------------
__global__ void k0_wvec(const float* __restrict__ W, const float* __restrict__ a,
                        float* __restrict__ w12) {
    const int in = threadIdx.x;          // 128 threads
    float s1 = 0.f, s2 = 0.f;
    for (int o = 0; o < 128; ++o) {
        float wv = W[o * 128 + in];
        s1 += wv * a[o];
        s2 += wv * a[o + 128];
    }
    w12[in] = s1;
    w12[128 + in] = s2;
}

// ---------------------------------------------------------------------------
// K1: Wh = h @ W^T -> whbT (bf16, [DIM][NN] col-major for MFMA B-frags)
// ---------------------------------------------------------------------------
__global__ __launch_bounds__(256) void k1_wh(const float* __restrict__ h,
                                             const float* __restrict__ W,
                                             __hip_bfloat16* __restrict__ whbT) {
    __shared__ float WT[128][129];
    __shared__ float h_s[16][128];
    __shared__ __hip_bfloat16 wt_s[128][16];

    const int tid = threadIdx.x;
    const int r0 = blockIdx.x * 16;

    for (int idx = tid; idx < 128 * 128; idx += 256) {
        int d = idx >> 7, k = idx & 127;
        WT[k][d] = W[idx];
    }
    for (int idx = tid; idx < 16 * 128; idx += 256)
        h_s[idx >> 7][idx & 127] = h[(size_t)(r0 + (idx >> 7)) * DIM + (idx & 127)];
    __syncthreads();

    const int d = tid & 127;
    const int g = tid >> 7;
    float acc[8] = {0, 0, 0, 0, 0, 0, 0, 0};
    for (int k = 0; k < 128; ++k) {
        float wv = WT[k][d];
        #pragma unroll
        for (int rr = 0; rr < 8; ++rr)
            acc[rr] += h_s[g * 8 + rr][k] * wv;
    }
    #pragma unroll
    for (int rr = 0; rr < 8; ++rr)
        wt_s[d][g * 8 + rr] = __float2bfloat16(acc[rr]);
    __syncthreads();
    for (int idx = tid; idx < 128 * 16; idx += 256) {
        int dd = idx >> 4, r = idx & 15;
        whbT[(size_t)dd * NN + r0 + r] = wt_s[dd][r];
    }
}

// ---------------------------------------------------------------------------
// K2a: per-row a1 = h.w1, a2 = h.w2, E1 = exp(a2), E2 = exp(0.2 a2)
// ---------------------------------------------------------------------------
__global__ __launch_bounds__(256) void k2a_rows(const float* __restrict__ h,
                                                const float* __restrict__ w12,
                                                float* __restrict__ a1g,
                                                float* __restrict__ a2g,
                                                float* __restrict__ E1g,
                                                float* __restrict__ E2g) {
    const int wid = threadIdx.x >> 6, lane = threadIdx.x & 63;
    const int i = blockIdx.x * 4 + wid;
    const float* hr = h + (size_t)i * DIM;
    float h0 = hr[lane], h1 = hr[lane + 64];
    float s1 = h0 * w12[lane] + h1 * w12[lane + 64];
    float s2 = h0 * w12[128 + lane] + h1 * w12[192 + lane];
    #pragma unroll
    for (int o = 32; o >= 1; o >>= 1) {
        s1 += __shfl_xor(s1, o, 64);
        s2 += __shfl_xor(s2, o, 64);
    }
    if (lane == 0) {
        a1g[i] = s1;
        a2g[i] = s2;
        E1g[i] = expf(s2);
        E2g[i] = expf(0.2f * s2);
    }
}

// ---------------------------------------------------------------------------
// SA: stream adj (1 wave per row, 32 waves/CU): build bitmask (global) +
// row softmax coefficients. No max-shift needed (values bounded, exp safe);
// no-neighbor rows detected by S1+S2 == 0.
// Bit layout: col j -> word (j>>8)*8 + ((j>>7)&1)*4 + (j&3), bit (j>>2)&31.
// Lanes 0/32 each store one 16B u32x4 per 256-col iteration.
// ---------------------------------------------------------------------------
__global__ __launch_bounds__(256) void sa_scan(const int* __restrict__ adj,
                                               const float* __restrict__ a1g,
                                               const float* __restrict__ a2g,
                                               const float* __restrict__ E1g,
                                               const float* __restrict__ E2g,
                                               unsigned* __restrict__ bm,
                                               float* __restrict__ crow) {
    const int wid = threadIdx.x >> 6, lane = threadIdx.x & 63;
    const int i = blockIdx.x * 4 + wid;
    const float a1i = a1g[i];
    const int* arow = adj + (size_t)i * NN;
    unsigned* brow = bm + (size_t)i * (NN / 32);

    float s1 = 0.f, s2 = 0.f;
    #pragma unroll 2
    for (int it = 0; it < NN / 256; ++it) {
        const int j0 = it * 256 + lane * 4;
        i32x4 v = __builtin_nontemporal_load((const i32x4*)(arow + j0));
        unsigned long long m0 = __ballot(v.x != 0);
        unsigned long long m1 = __ballot(v.y != 0);
        unsigned long long m2 = __ballot(v.z != 0);
        unsigned long long m3 = __ballot(v.w != 0);
        if (lane == 0) {
            u32x4 w;
            w.x = (unsigned)m0; w.y = (unsigned)m1;
            w.z = (unsigned)m2; w.w = (unsigned)m3;
            *(u32x4*)(brow + it * 8) = w;
        } else if (lane == 32) {
            u32x4 w;
            w.x = (unsigned)(m0 >> 32); w.y = (unsigned)(m1 >> 32);
            w.z = (unsigned)(m2 >> 32); w.w = (unsigned)(m3 >> 32);
            *(u32x4*)(brow + it * 8 + 4) = w;
        }
        f32x4 x2 = *(const f32x4*)(a2g + j0);
        f32x4 e1 = *(const f32x4*)(E1g + j0);
        f32x4 e2 = *(const f32x4*)(E2g + j0);
        bool px;
        px = (a1i + x2.x >= 0.f);
        s1 += (v.x && px) ? e1.x : 0.f;  s2 += (v.x && !px) ? e2.x : 0.f;
        px = (a1i + x2.y >= 0.f);
        s1 += (v.y && px) ? e1.y : 0.f;  s2 += (v.y && !px) ? e2.y : 0.f;
        px = (a1i + x2.z >= 0.f);
        s1 += (v.z && px) ? e1.z : 0.f;  s2 += (v.z && !px) ? e2.z : 0.f;
        px = (a1i + x2.w >= 0.f);
        s1 += (v.w && px) ? e1.w : 0.f;  s2 += (v.w && !px) ? e2.w : 0.f;
    }
    #pragma unroll
    for (int o = 32; o >= 1; o >>= 1) {
        s1 += __shfl_xor(s1, o, 64);
        s2 += __shfl_xor(s2, o, 64);
    }
    if (lane == 0) {
        float c1 = 0.f, c2 = 0.f;
        if (s1 + s2 > 0.f) {
            float e1v = expf(a1i);
            float e2v = expf(0.2f * a1i);
            float S = e1v * s1 + e2v * s2;
            c1 = e1v / S;
            c2 = e2v / S;
        }
        crow[i * 4 + 0] = c1;
        crow[i * 4 + 1] = c2;
        crow[i * 4 + 2] = a1i;
    }
}

// ---------------------------------------------------------------------------
// SB: fused alpha-write + PV MFMA, split-K. grid (NN/RPB, KS), 512 threads.
// Per 256-col chunk: compute 32x256 alpha (nontemporal f32 store + bf16 LDS
// stage, double-buffered), then 8 waves x (2 row-tiles x 8 k-steps) MFMA.
// ---------------------------------------------------------------------------
__global__ __launch_bounds__(512) void sb_pv(const unsigned* __restrict__ bm,
                                             const float* __restrict__ crowG,
                                             const float* __restrict__ a2g,
                                             const float* __restrict__ E1g,
                                             const float* __restrict__ E2g,
                                             const __hip_bfloat16* __restrict__ whbT,
                                             float* __restrict__ alpha,
                                             float* __restrict__ part) {
    __shared__ unsigned bmL[RPB][KSL / 32];              // 8 KB
    __shared__ __hip_bfloat16 abuf[2][RPB][KC + 8];      // 33.8 KB
    __shared__ float crowL[RPB][4];                      // 512 B

    const int tid = threadIdx.x;
    const int wv = tid >> 6, lane = tid & 63;
    const int r0 = blockIdx.x * RPB;
    const int ks = blockIdx.y;
    const int k0 = ks * KSL;

    {   // preload bitmask slice + row coefficients
        const int r = tid >> 4, wq = (tid & 15) << 2;    // 32 rows x 16 quads
        *(u32x4*)(&bmL[r][wq]) =
            *(const u32x4*)(bm + (size_t)(r0 + r) * (NN / 32) + ks * (KSL / 32) + wq);
        if (tid < RPB * 4)
            crowL[tid >> 2][tid & 3] = crowG[(r0 + (tid >> 2)) * 4 + (tid & 3)];
    }
    __syncthreads();

    f32x4 acc0 = (f32x4){0.f, 0.f, 0.f, 0.f};
    f32x4 acc1 = (f32x4){0.f, 0.f, 0.f, 0.f};
    const int n0 = wv * 16;
    const short* bptr = reinterpret_cast<const short*>(whbT) +
                        (size_t)(n0 + (lane & 15)) * NN + k0 + 8 * (lane >> 4);

    for (int kc = 0; kc < KSL; kc += KC) {
        const int dbuf = (kc >> 8) & 1;
        #pragma unroll
        for (int v = 0; v < 4; ++v) {
            const int vid = v * 512 + tid;
            const int r = vid >> 6;                      // 64 threads per row
            const int c4 = (vid & 63) << 2;
            const int jl = kc + c4;                      // col within slice
            const int j = k0 + jl;                       // global col
            const int wb = ((jl >> 8) << 3) + (((jl >> 7) & 1) << 2);
            i32x4 w4 = *(const i32x4*)(&bmL[r][wb]);     // broadcast within half-wave
            const unsigned p = (jl >> 2) & 31;
            const float c1 = crowL[r][0], c2 = crowL[r][1], a1i = crowL[r][2];
            f32x4 x2 = *(const f32x4*)(a2g + j);
            f32x4 e1 = *(const f32x4*)(E1g + j);
            f32x4 e2 = *(const f32x4*)(E2g + j);
            f32x4 al;
            al.x = ((w4.x >> p) & 1) ? ((a1i + x2.x >= 0.f) ? c1 * e1.x : c2 * e2.x) : 0.f;
            al.y = ((w4.y >> p) & 1) ? ((a1i + x2.y >= 0.f) ? c1 * e1.y : c2 * e2.y) : 0.f;
            al.z = ((w4.z >> p) & 1) ? ((a1i + x2.z >= 0.f) ? c1 * e1.z : c2 * e2.z) : 0.f;
            al.w = ((w4.w >> p) & 1) ? ((a1i + x2.w >= 0.f) ? c1 * e1.w : c2 * e2.w) : 0.f;
            __builtin_nontemporal_store(al, (f32x4*)(alpha + (size_t)(r0 + r) * NN + j));
            u16x4 ub;
            ub.x = f2bf(al.x); ub.y = f2bf(al.y); ub.z = f2bf(al.z); ub.w = f2bf(al.w);
            *(u16x4*)(&abuf[dbuf][r][c4]) = ub;
        }
        __syncthreads();
        #pragma unroll
        for (int kk = 0; kk < KC; kk += 32) {
            bf16x8 bf = *(const bf16x8*)(bptr + kc + kk);
            bf16x8 a0 = *(const bf16x8*)(&abuf[dbuf][lane & 15][kk + 8 * (lane >> 4)]);
            bf16x8 a1f = *(const bf16x8*)(&abuf[dbuf][16 + (lane & 15)][kk + 8 * (lane >> 4)]);
            acc0 = __builtin_amdgcn_mfma_f32_16x16x32_bf16(a0, bf, acc0, 0, 0, 0);
            acc1 = __builtin_amdgcn_mfma_f32_16x16x32_bf16(a1f, bf, acc1, 0, 0, 0);
        }
    }

    float* pb = part + (size_t)ks * NN * DIM;
    const int col = n0 + (lane & 15);
    const int rb = (lane >> 4) * 4;
    #pragma unroll
    for (int q = 0; q < 4; ++q) {
        pb[(size_t)(r0 + rb + q) * DIM + col] = acc0[q];
        pb[(size_t)(r0 + 16 + rb + q) * DIM + col] = acc1[q];
    }
}

// ---------------------------------------------------------------------------
// K5: reduce split-K partials -> out
// ---------------------------------------------------------------------------
__global__ __launch_bounds__(256) void k5_reduce(const float* __restrict__ part,
                                                 float* __restrict__ out) {
    const int idx = blockIdx.x * 256 + threadIdx.x;
    float s = 0.f;
    #pragma unroll
    for (int ks = 0; ks < KS; ++ks) s += part[(size_t)ks * NN * DIM + idx];
    out[idx] = s;
}

// ---------------------------------------------------------------------------
extern "C" void kernel_launch(void* const* d_in, const int* in_sizes, int n_in,
                              void* d_out, int out_size, void* d_ws, size_t ws_size,
                              hipStream_t stream) {
    const float* h   = (const float*)d_in[0];
    const int*   adj = (const int*)d_in[1];
    const float* W   = (const float*)d_in[2];
    const float* a   = (const float*)d_in[3];

    float* out   = (float*)d_out;
    float* alpha = out + (size_t)NN * DIM;

    char* ws = (char*)d_ws;
    __hip_bfloat16* whbT = (__hip_bfloat16*)(ws);          // 2 MB
    float* a1g  = (float*)(ws + 0x200000);                 // 32 KB each
    float* a2g  = (float*)(ws + 0x208000);
    float* E1g  = (float*)(ws + 0x210000);
    float* E2g  = (float*)(ws + 0x218000);
    float* w12  = (float*)(ws + 0x220000);                 // 1 KB
    float* crow = (float*)(ws + 0x228000);                 // 128 KB
    unsigned* bm = (unsigned*)(ws + 0x280000);             // 8 MB
    float* part = (float*)(ws + 0xA80000);                 // 16 MB

    k0_wvec<<<1, 128, 0, stream>>>(W, a, w12);
    k1_wh<<<NN / 16, 256, 0, stream>>>(h, W, whbT);
    k2a_rows<<<NN / 4, 256, 0, stream>>>(h, w12, a1g, a2g, E1g, E2g);
    sa_scan<<<NN / 4, 256, 0, stream>>>(adj, a1g, a2g, E1g, E2g, bm, crow);
    sb_pv<<<dim3(NN / RPB, KS), 512, 0, stream>>>(bm, crow, a2g, E1g, E2g, whbT, alpha, part);
    k5_reduce<<<NN * DIM / 256, 256, 0, stream>>>(part, out);
}